// Round 5
// baseline (26.827 us; speedup 1.0000x reference)
//
#include <hip/hip_runtime.h>

#define R 128
#define C 256
#define P 7
#define HW 64
#define LSTRIDE 65   // padded slab row stride

__global__ __launch_bounds__(256) void
roi_pool_kernel(const float* __restrict__ x,
                const int* __restrict__ rois,
                float* __restrict__ out) {
    const int lane = threadIdx.x & 63;
    const int wid  = __builtin_amdgcn_readfirstlane(threadIdx.x >> 6);
    const int b = blockIdx.x;
    // Block's 4 waves share ONE channel (L1 reuse), cover 4 ROIs.
    const int c = b & (C - 1);
    const int r = ((b >> 8) << 2) + wid;

    __shared__ float vmbuf[4][P * LSTRIDE];
    float* slab = vmbuf[wid];

    const int rx = rois[r * 4 + 0];          // scalar loads (r is SGPR)
    const int ry = rois[r * 4 + 1];
    const int rw = rois[r * 4 + 2];
    const int rh = rois[r * 4 + 3];

    // Match JAX: f32 rn divide; floor(coord + i*rl) with separate rn mul+add.
    const float rlx = (float)rw / 7.0f;
    const float rly = (float)rh / 7.0f;
    const int kw = __builtin_amdgcn_readfirstlane((int)rlx);  // floor(rl) >= 1
    const int kh = __builtin_amdgcn_readfirstlane((int)rly);

    // Vector-parallel band starts: lane plays py for lanes 0..6, then readlane.
    const int syv = (int)floorf(__fadd_rn((float)ry, __fmul_rn((float)lane, rly)));

    const float* xc = x + (size_t)c * (HW * HW);
    const float NEG = -3.402823466e38f;

    // ---- Phase 1: vertical band maxes; lane = column (coalesced loads) ----
    #pragma unroll
    for (int py = 0; py < P; ++py) {
        const int sy = __builtin_amdgcn_readlane(syv, py);   // SGPR
        const float* p = xc + sy * HW + lane;
        float vm = NEG;
        #pragma unroll
        for (int j = 0; j < 8; ++j)
            if (j < kh)                       // wave-uniform SALU branch
                vm = fmaxf(vm, p[j * HW]);    // saddr + imm offset
        slab[py * LSTRIDE + lane] = vm;       // stride-1 ds_write (conflict-free)
    }

    // ---- Phase 2: one lane per output bin; batched ds_reads ----
    if (lane < P * P) {
        const int py = lane / 7;
        const int px = lane - py * 7;
        const int sx = (int)floorf(__fadd_rn((float)rx, __fmul_rn((float)px, rlx)));
        const float* w = slab + py * LSTRIDE + sx;
        float m = NEG;
        #pragma unroll
        for (int j = 0; j < 8; ++j)
            if (j < kw)                       // wave-uniform SALU branch
                m = fmaxf(m, w[j]);           // ds_read, imm offsets
        out[(size_t)(r * C + c) * (P * P) + lane] = m;  // 49 consecutive floats
    }
}

extern "C" void kernel_launch(void* const* d_in, const int* in_sizes, int n_in,
                              void* d_out, int out_size, void* d_ws, size_t ws_size,
                              hipStream_t stream) {
    const float* x = (const float*)d_in[0];
    const int* rois = (const int*)d_in[1];
    float* out = (float*)d_out;

    const int grid = (R * C) / 4;  // 8192 blocks: 4 waves = 4 ROIs, 1 channel
    roi_pool_kernel<<<grid, 256, 0, stream>>>(x, rois, out);
}